// Round 4
// baseline (127.413 us; speedup 1.0000x reference)
//
#include <hip/hip_runtime.h>

#define K 8

// clang native vector types — required for __builtin_nontemporal_load/store
typedef float vfloat4 __attribute__((ext_vector_type(4)));
typedef int   vint4   __attribute__((ext_vector_type(4)));

// ---------- prepack: points+normals -> 32B interleaved records in ws ----------
// rec[2i]   = {px, py, pz, 0}
// rec[2i+1] = {nx, ny, nz, 0}
__global__ __launch_bounds__(256) void pack_pn_kernel(
    const float* __restrict__ points,
    const float* __restrict__ normals,
    vfloat4*     __restrict__ rec,
    int P)
{
    const int i = blockIdx.x * blockDim.x + threadIdx.x;
    if (i >= P) return;
    const size_t b = (size_t)i * 3;
    vfloat4 pv = {points[b],  points[b + 1],  points[b + 2],  0.0f};
    vfloat4 nv = {normals[b], normals[b + 1], normals[b + 2], 0.0f};
    rec[2 * i]     = pv;
    rec[2 * i + 1] = nv;
}

template <bool PACKED>
__global__ __launch_bounds__(256) void shading_compositor_kernel(
    const int*    __restrict__ idx,
    const float*  __restrict__ dists,
    const float*  __restrict__ points,
    const float*  __restrict__ normals,
    const vfloat4* __restrict__ rec,
    const float*  __restrict__ light_location,
    const float*  __restrict__ light_ambient,
    const float*  __restrict__ light_diffuse,
    const float*  __restrict__ light_specular,
    const float*  __restrict__ mat_ambient,
    const float*  __restrict__ mat_diffuse,
    const float*  __restrict__ mat_specular,
    const float*  __restrict__ camera_position,
    const int*    __restrict__ shininess_p,
    float*        __restrict__ out,
    int n_pix)
{
    const int p = blockIdx.x * blockDim.x + threadIdx.x;
    if (p >= n_pix) return;

    // ---- streamed per-pixel inputs (nontemporal: don't evict the gather table) ----
    const vint4*   idxv = reinterpret_cast<const vint4*>(idx   + (size_t)p * K);
    const vfloat4* dstv = reinterpret_cast<const vfloat4*>(dists + (size_t)p * K);
    vint4   i0 = __builtin_nontemporal_load(idxv);
    vint4   i1 = __builtin_nontemporal_load(idxv + 1);
    vfloat4 d0 = __builtin_nontemporal_load(dstv);
    vfloat4 d1 = __builtin_nontemporal_load(dstv + 1);

    int   ik[K] = {i0.x, i0.y, i0.z, i0.w, i1.x, i1.y, i1.z, i1.w};
    float dk[K] = {d0.x, d0.y, d0.z, d0.w, d1.x, d1.y, d1.z, d1.w};

    // ---- phase 1: issue ALL 16 gather loads (MLP=16) ----
    vfloat4 pr[K], nr[K];
#pragma unroll
    for (int k = 0; k < K; ++k) {
        const int ii = (ik[k] < 0) ? 0 : ik[k];
        if (PACKED) {
            const vfloat4* r = rec + 2 * (size_t)ii;
            pr[k] = r[0];
            nr[k] = r[1];
        } else {
            const size_t base = (size_t)ii * 3;
            vfloat4 pv = {points[base], points[base + 1], points[base + 2], 0.0f};
            vfloat4 nv = {normals[base], normals[base + 1], normals[base + 2], 0.0f};
            pr[k] = pv;
            nr[k] = nv;
        }
    }
#if defined(__has_builtin)
#if __has_builtin(__builtin_amdgcn_sched_barrier)
    __builtin_amdgcn_sched_barrier(0);   // keep the load phase ahead of compute
#endif
#endif

    // ---- uniform constants (scalar loads) ----
    const float Lx = light_location[0], Ly = light_location[1], Lz = light_location[2];
    const float Cx = camera_position[0], Cy = camera_position[1], Cz = camera_position[2];
    const float amb0 = light_ambient[0] * mat_ambient[0];
    const float amb1 = light_ambient[1] * mat_ambient[1];
    const float amb2 = light_ambient[2] * mat_ambient[2];
    const float dif0 = light_diffuse[0] * mat_diffuse[0];
    const float dif1 = light_diffuse[1] * mat_diffuse[1];
    const float dif2 = light_diffuse[2] * mat_diffuse[2];
    const float spc0 = light_specular[0] * mat_specular[0];
    const float spc1 = light_specular[1] * mat_specular[1];
    const float spc2 = light_specular[2] * mat_specular[2];
    const int   shin = shininess_p[0];

    // ---- distance weights ----
    float w[K];
    float wsum = 0.f;
#pragma unroll
    for (int k = 0; k < K; ++k) {
        float d = dk[k];
        float m = (d != -1.0f) ? d : 0.0f;
        w[k] = m;
        wsum += fabsf(m);
    }
    const float winv = 1.0f / fmaxf(wsum, 1e-12f);

    float acc0 = 0.f, acc1 = 0.f, acc2 = 0.f;

#pragma unroll
    for (int k = 0; k < K; ++k) {
        const float px = pr[k].x, py = pr[k].y, pz = pr[k].z;
        const float nx = nr[k].x, ny = nr[k].y, nz = nr[k].z;

        float lx = Lx - px, ly = Ly - py, lz = Lz - pz;
        float ll = lx * lx + ly * ly + lz * lz;
        float li = (ll > 1e-12f) ? rsqrtf(ll) : 1e6f;
        lx *= li; ly *= li; lz *= li;

        const float cosv = nx * lx + ny * ly + nz * lz;

        float vx = Cx - px, vy = Cy - py, vz = Cz - pz;
        float vv = vx * vx + vy * vy + vz * vz;
        float vi = (vv > 1e-12f) ? rsqrtf(vv) : 1e6f;
        vx *= vi; vy *= vi; vz *= vi;

        const float c2 = 2.0f * cosv;
        const float rx = c2 * nx - lx;
        const float ry = c2 * ny - ly;
        const float rz = c2 * nz - lz;

        float alpha = fmaxf(vx * rx + vy * ry + vz * rz, 0.0f);
        if (!(cosv > 0.0f)) alpha = 0.0f;

        // alpha ** shin; fast path for the power-of-two case
        float sp;
        if (shin == 64) {
            float b = alpha;
            b *= b; b *= b; b *= b; b *= b; b *= b; b *= b;  // alpha^64
            sp = b;
        } else {
            sp = 1.0f;
            float b = alpha;
            int e = shin;
            while (e > 0) {
                if (e & 1) sp *= b;
                b *= b;
                e >>= 1;
            }
        }

        const float rc = fmaxf(cosv, 0.0f);
        const float wk = w[k];
        acc0 += wk * (amb0 + dif0 * rc + spc0 * sp);
        acc1 += wk * (amb1 + dif1 * rc + spc1 * sp);
        acc2 += wk * (amb2 + dif2 * rc + spc2 * sp);
    }

    float* o = out + (size_t)p * 3;
    __builtin_nontemporal_store(acc0 * winv, o);
    __builtin_nontemporal_store(acc1 * winv, o + 1);
    __builtin_nontemporal_store(acc2 * winv, o + 2);
}

extern "C" void kernel_launch(void* const* d_in, const int* in_sizes, int n_in,
                              void* d_out, int out_size, void* d_ws, size_t ws_size,
                              hipStream_t stream) {
    const int*   idx             = (const int*)d_in[0];
    const float* dists           = (const float*)d_in[1];
    const float* points          = (const float*)d_in[2];
    const float* normals         = (const float*)d_in[3];
    const float* light_location  = (const float*)d_in[4];
    const float* light_ambient   = (const float*)d_in[5];
    const float* light_diffuse   = (const float*)d_in[6];
    const float* light_specular  = (const float*)d_in[7];
    const float* mat_ambient     = (const float*)d_in[8];
    const float* mat_diffuse     = (const float*)d_in[9];
    const float* mat_specular    = (const float*)d_in[10];
    const float* camera_position = (const float*)d_in[11];
    const int*   shininess       = (const int*)d_in[12];
    float*       out             = (float*)d_out;

    const int n_pix = in_sizes[0] / K;       // N*H*W
    const int P     = in_sizes[2] / 3;       // number of points

    const int block = 256;
    const int grid  = (n_pix + block - 1) / block;

    const size_t need = (size_t)P * 2 * sizeof(vfloat4);
    if (ws_size >= need) {
        vfloat4* rec = (vfloat4*)d_ws;
        pack_pn_kernel<<<(P + block - 1) / block, block, 0, stream>>>(points, normals, rec, P);
        shading_compositor_kernel<true><<<grid, block, 0, stream>>>(
            idx, dists, points, normals, rec, light_location, light_ambient,
            light_diffuse, light_specular, mat_ambient, mat_diffuse,
            mat_specular, camera_position, shininess, out, n_pix);
    } else {
        shading_compositor_kernel<false><<<grid, block, 0, stream>>>(
            idx, dists, points, normals, nullptr, light_location, light_ambient,
            light_diffuse, light_specular, mat_ambient, mat_diffuse,
            mat_specular, camera_position, shininess, out, n_pix);
    }
}

// Round 5
// 125.018 us; speedup vs baseline: 1.0192x; 1.0192x over previous
//
#include <hip/hip_runtime.h>

#define K 8

// clang native vector types — required for __builtin_nontemporal_load/store
typedef float vfloat4 __attribute__((ext_vector_type(4)));
typedef int   vint4   __attribute__((ext_vector_type(4)));

// ---------- prepack: {pos.xyz f32, oct16x16(normal)} -> ONE 16B record ----------
__global__ __launch_bounds__(256) void pack_pn_kernel(
    const float* __restrict__ points,
    const float* __restrict__ normals,
    vfloat4*     __restrict__ rec,
    int P)
{
    const int i = blockIdx.x * blockDim.x + threadIdx.x;
    if (i >= P) return;
    const size_t b = (size_t)i * 3;
    const float nx = normals[b], ny = normals[b + 1], nz = normals[b + 2];

    // octahedral encode (input is unit-length)
    const float s  = 1.0f / (fabsf(nx) + fabsf(ny) + fabsf(nz));
    float ox = nx * s, oy = ny * s;
    if (nz < 0.0f) {
        const float tx = (1.0f - fabsf(oy)) * (ox >= 0.0f ? 1.0f : -1.0f);
        const float ty = (1.0f - fabsf(ox)) * (oy >= 0.0f ? 1.0f : -1.0f);
        ox = tx; oy = ty;
    }
    const unsigned ux = (unsigned)(fminf(fmaxf(ox * 0.5f + 0.5f, 0.0f), 1.0f) * 65535.0f + 0.5f);
    const unsigned uy = (unsigned)(fminf(fmaxf(oy * 0.5f + 0.5f, 0.0f), 1.0f) * 65535.0f + 0.5f);
    const unsigned pk = ux | (uy << 16);

    vfloat4 r = {points[b], points[b + 1], points[b + 2], __uint_as_float(pk)};
    rec[i] = r;
}

template <bool PACKED>
__global__ __launch_bounds__(256) void shading_compositor_kernel(
    const int*    __restrict__ idx,
    const float*  __restrict__ dists,
    const float*  __restrict__ points,
    const float*  __restrict__ normals,
    const vfloat4* __restrict__ rec,
    const float*  __restrict__ light_location,
    const float*  __restrict__ light_ambient,
    const float*  __restrict__ light_diffuse,
    const float*  __restrict__ light_specular,
    const float*  __restrict__ mat_ambient,
    const float*  __restrict__ mat_diffuse,
    const float*  __restrict__ mat_specular,
    const float*  __restrict__ camera_position,
    const int*    __restrict__ shininess_p,
    float*        __restrict__ out,
    int n_pix)
{
    const int p = blockIdx.x * blockDim.x + threadIdx.x;
    if (p >= n_pix) return;

    // ---- streamed per-pixel inputs (nontemporal: read-once, keep table in cache) ----
    const vint4*   idxv = reinterpret_cast<const vint4*>(idx   + (size_t)p * K);
    const vfloat4* dstv = reinterpret_cast<const vfloat4*>(dists + (size_t)p * K);
    vint4   i0 = __builtin_nontemporal_load(idxv);
    vint4   i1 = __builtin_nontemporal_load(idxv + 1);
    vfloat4 d0 = __builtin_nontemporal_load(dstv);
    vfloat4 d1 = __builtin_nontemporal_load(dstv + 1);

    int   ik[K] = {i0.x, i0.y, i0.z, i0.w, i1.x, i1.y, i1.z, i1.w};
    float dk[K] = {d0.x, d0.y, d0.z, d0.w, d1.x, d1.y, d1.z, d1.w};

    // ---- gather phase: ONE 16B load per sample (8 divergent transactions) ----
    vfloat4 rr[K];
#pragma unroll
    for (int k = 0; k < K; ++k) {
        const int ii = (ik[k] < 0) ? 0 : ik[k];
        if (PACKED) {
            rr[k] = rec[(size_t)ii];
        } else {
            const size_t base = (size_t)ii * 3;
            vfloat4 pv = {points[base], points[base + 1], points[base + 2], 0.0f};
            rr[k] = pv;
        }
    }
    // fallback path: normals gathered separately (unpacked)
    vfloat4 nrf[K];
    if (!PACKED) {
#pragma unroll
        for (int k = 0; k < K; ++k) {
            const int ii = (ik[k] < 0) ? 0 : ik[k];
            const size_t base = (size_t)ii * 3;
            vfloat4 nv = {normals[base], normals[base + 1], normals[base + 2], 0.0f};
            nrf[k] = nv;
        }
    }

    // ---- uniform constants (scalar loads) ----
    const float Lx = light_location[0], Ly = light_location[1], Lz = light_location[2];
    const float Cx = camera_position[0], Cy = camera_position[1], Cz = camera_position[2];
    const float amb0 = light_ambient[0] * mat_ambient[0];
    const float amb1 = light_ambient[1] * mat_ambient[1];
    const float amb2 = light_ambient[2] * mat_ambient[2];
    const float dif0 = light_diffuse[0] * mat_diffuse[0];
    const float dif1 = light_diffuse[1] * mat_diffuse[1];
    const float dif2 = light_diffuse[2] * mat_diffuse[2];
    const float spc0 = light_specular[0] * mat_specular[0];
    const float spc1 = light_specular[1] * mat_specular[1];
    const float spc2 = light_specular[2] * mat_specular[2];
    const int   shin = shininess_p[0];

    // ---- distance weights ----
    float w[K];
    float wsum = 0.f;
#pragma unroll
    for (int k = 0; k < K; ++k) {
        float d = dk[k];
        float m = (d != -1.0f) ? d : 0.0f;
        w[k] = m;
        wsum += fabsf(m);
    }
    const float winv = 1.0f / fmaxf(wsum, 1e-12f);

    float acc0 = 0.f, acc1 = 0.f, acc2 = 0.f;

#pragma unroll
    for (int k = 0; k < K; ++k) {
        const float px = rr[k].x, py = rr[k].y, pz = rr[k].z;

        float nx, ny, nz;
        if (PACKED) {
            // octahedral decode + renormalize
            const unsigned pk = __float_as_uint(rr[k].w);
            const float ox = (float)(pk & 0xffffu) * (2.0f / 65535.0f) - 1.0f;
            const float oy = (float)(pk >> 16)     * (2.0f / 65535.0f) - 1.0f;
            float zz = 1.0f - fabsf(ox) - fabsf(oy);
            const float t = fmaxf(-zz, 0.0f);
            float xx = ox + ((ox >= 0.0f) ? -t : t);
            float yy = oy + ((oy >= 0.0f) ? -t : t);
            const float ni = rsqrtf(xx * xx + yy * yy + zz * zz);
            nx = xx * ni; ny = yy * ni; nz = zz * ni;
        } else {
            nx = nrf[k].x; ny = nrf[k].y; nz = nrf[k].z;
        }

        float lx = Lx - px, ly = Ly - py, lz = Lz - pz;
        float ll = lx * lx + ly * ly + lz * lz;
        float li = (ll > 1e-12f) ? rsqrtf(ll) : 1e6f;
        lx *= li; ly *= li; lz *= li;

        const float cosv = nx * lx + ny * ly + nz * lz;

        float vx = Cx - px, vy = Cy - py, vz = Cz - pz;
        float vv = vx * vx + vy * vy + vz * vz;
        float vi = (vv > 1e-12f) ? rsqrtf(vv) : 1e6f;
        vx *= vi; vy *= vi; vz *= vi;

        const float c2 = 2.0f * cosv;
        const float rx = c2 * nx - lx;
        const float ry = c2 * ny - ly;
        const float rz = c2 * nz - lz;

        float alpha = fmaxf(vx * rx + vy * ry + vz * rz, 0.0f);
        if (!(cosv > 0.0f)) alpha = 0.0f;

        // alpha ** shin; fast path for the power-of-two case
        float sp;
        if (shin == 64) {
            float b = alpha;
            b *= b; b *= b; b *= b; b *= b; b *= b; b *= b;  // alpha^64
            sp = b;
        } else {
            sp = 1.0f;
            float b = alpha;
            int e = shin;
            while (e > 0) {
                if (e & 1) sp *= b;
                b *= b;
                e >>= 1;
            }
        }

        const float rc = fmaxf(cosv, 0.0f);
        const float wk = w[k];
        acc0 += wk * (amb0 + dif0 * rc + spc0 * sp);
        acc1 += wk * (amb1 + dif1 * rc + spc1 * sp);
        acc2 += wk * (amb2 + dif2 * rc + spc2 * sp);
    }

    float* o = out + (size_t)p * 3;
    __builtin_nontemporal_store(acc0 * winv, o);
    __builtin_nontemporal_store(acc1 * winv, o + 1);
    __builtin_nontemporal_store(acc2 * winv, o + 2);
}

extern "C" void kernel_launch(void* const* d_in, const int* in_sizes, int n_in,
                              void* d_out, int out_size, void* d_ws, size_t ws_size,
                              hipStream_t stream) {
    const int*   idx             = (const int*)d_in[0];
    const float* dists           = (const float*)d_in[1];
    const float* points          = (const float*)d_in[2];
    const float* normals         = (const float*)d_in[3];
    const float* light_location  = (const float*)d_in[4];
    const float* light_ambient   = (const float*)d_in[5];
    const float* light_diffuse   = (const float*)d_in[6];
    const float* light_specular  = (const float*)d_in[7];
    const float* mat_ambient     = (const float*)d_in[8];
    const float* mat_diffuse     = (const float*)d_in[9];
    const float* mat_specular    = (const float*)d_in[10];
    const float* camera_position = (const float*)d_in[11];
    const int*   shininess       = (const int*)d_in[12];
    float*       out             = (float*)d_out;

    const int n_pix = in_sizes[0] / K;       // N*H*W
    const int P     = in_sizes[2] / 3;       // number of points

    const int block = 256;
    const int grid  = (n_pix + block - 1) / block;

    const size_t need = (size_t)P * sizeof(vfloat4);
    if (ws_size >= need) {
        vfloat4* rec = (vfloat4*)d_ws;
        pack_pn_kernel<<<(P + block - 1) / block, block, 0, stream>>>(points, normals, rec, P);
        shading_compositor_kernel<true><<<grid, block, 0, stream>>>(
            idx, dists, points, normals, rec, light_location, light_ambient,
            light_diffuse, light_specular, mat_ambient, mat_diffuse,
            mat_specular, camera_position, shininess, out, n_pix);
    } else {
        shading_compositor_kernel<false><<<grid, block, 0, stream>>>(
            idx, dists, points, normals, nullptr, light_location, light_ambient,
            light_diffuse, light_specular, mat_ambient, mat_diffuse,
            mat_specular, camera_position, shininess, out, n_pix);
    }
}